// Round 3
// baseline (11638.152 us; speedup 1.0000x reference)
//
#include <hip/hip_runtime.h>
#include <hip/hip_bf16.h>
#include <cmath>
#include <cstddef>

// Problem constants (from reference)
#define NN 100000
#define HH 128
#define EE 1600000
#define NH (NN * HH)
#define ALPHA_C 0.1f
#define THETA_C 0.5f
#define EPS_C 1e-5f

constexpr int TRG = 64;        // rows per GEMM block
constexpr int KST = 68;        // LDS stride (floats): b128-aligned, 2-way max
constexpr int BUFF = 64 * KST; // floats per K-half buffer (4352)
constexpr int SCAN_B = 256;
constexpr int NBLK = (NN + SCAN_B - 1) / SCAN_B;   // 391 scan blocks

// ---------------------------------------------------------------------------
__global__ __launch_bounds__(256) void zero_int_k(int* __restrict__ p, int n) {
    int i = blockIdx.x * 256 + threadIdx.x;
    if (i < n) p[i] = 0;
}
__global__ __launch_bounds__(256) void zero_f4_k(float4* __restrict__ p, int n4) {
    int i = blockIdx.x * 256 + threadIdx.x;
    if (i < n4) p[i] = float4{0.f, 0.f, 0.f, 0.f};
}

// ---------------------------------------------------------------------------
// Index dtype detection: int64 (values < 2^31) -> every odd 32-bit word is 0.
__global__ void detect_idx64(const int* __restrict__ p, int* __restrict__ flag) {
    int any = 0;
    for (int i = 0; i < 64; ++i) any |= p[2 * i + 1];
    *flag = (any == 0) ? 1 : 0;
}

__device__ __forceinline__ int load_idx(const void* p, int e, int is64) {
    return is64 ? (int)((const long long*)p)[e] : ((const int*)p)[e];
}

// ---------------------------------------------------------------------------
// CSR build: histogram of dst
__global__ __launch_bounds__(256) void hist_k(
    const void* __restrict__ dstp, const int* __restrict__ flag,
    int* __restrict__ hist)
{
    int e = blockIdx.x * 256 + threadIdx.x;
    if (e >= EE) return;
    atomicAdd(&hist[load_idx(dstp, e, *flag)], 1);
}

__global__ __launch_bounds__(SCAN_B) void scan1_k(
    const int* __restrict__ hist, int* __restrict__ incl, int* __restrict__ bsum)
{
    __shared__ int sh[SCAN_B];
    int t = threadIdx.x;
    int i = blockIdx.x * SCAN_B + t;
    int v = (i < NN) ? hist[i] : 0;
    sh[t] = v;
    __syncthreads();
    for (int off = 1; off < SCAN_B; off <<= 1) {
        int x = (t >= off) ? sh[t - off] : 0;
        __syncthreads();
        sh[t] += x;
        __syncthreads();
    }
    if (i < NN) incl[i] = sh[t];
    if (t == SCAN_B - 1) bsum[blockIdx.x] = sh[t];
}

__global__ __launch_bounds__(512) void scan2_k(int* __restrict__ bsum) {
    __shared__ int sh[512];
    int t = threadIdx.x;
    sh[t] = (t < NBLK) ? bsum[t] : 0;
    __syncthreads();
    for (int off = 1; off < 512; off <<= 1) {
        int x = (t >= off) ? sh[t - off] : 0;
        __syncthreads();
        sh[t] += x;
        __syncthreads();
    }
    if (t < NBLK) bsum[t] = sh[t];
}

__global__ __launch_bounds__(SCAN_B) void scan3_k(
    const int* __restrict__ hist, const int* __restrict__ incl,
    const int* __restrict__ bsum, int* __restrict__ row_ptr,
    int* __restrict__ cursor)
{
    int b = blockIdx.x;
    int i = b * SCAN_B + threadIdx.x;
    if (i < NN) {
        int ex = incl[i] - hist[i] + (b > 0 ? bsum[b - 1] : 0);
        row_ptr[i] = ex;
        cursor[i] = ex;
    }
    if (i == 0) row_ptr[NN] = EE;
}

__global__ __launch_bounds__(256) void fill_k(
    const void* __restrict__ srcp, const void* __restrict__ dstp,
    const int* __restrict__ flag, int* __restrict__ cursor,
    int* __restrict__ sorted_src)
{
    int e = blockIdx.x * 256 + threadIdx.x;
    if (e >= EE) return;
    int is64 = *flag;
    int d = load_idx(dstp, e, is64);
    int pos = atomicAdd(&cursor[d], 1);
    sorted_src[pos] = load_idx(srcp, e, is64);
}

// ---------------------------------------------------------------------------
// CSR gather + residual fold: msg[n] = (1-ALPHA)*sum_{e in n}(act(z[src]))
//                                       + ALPHA*x0[n]
// act = BN+ReLU derived in-register from raw sum/sumsq stats when stats!=null.
// 4 edges in flight per wave (half-split x 2-deep unroll) for MLP.
// (Verified passing in round 2.)
__global__ __launch_bounds__(256) void gather_k(
    const float* __restrict__ z, const int* __restrict__ row_ptr,
    const int* __restrict__ sorted_src,
    const float* __restrict__ stats,    // [256]: sum, sumsq; null = no BN
    const float* __restrict__ gamma, const float* __restrict__ beta,
    const float* __restrict__ resid,    // x0
    float* __restrict__ msg)
{
    int node = blockIdx.x * 4 + (threadIdx.x >> 6);
    if (node >= NN) return;
    int lane = threadIdx.x & 63;
    int half = lane >> 5;        // which edge stream of the pair
    int c4 = lane & 31;          // float4 column index

    // issue residual load early; consumed at the very end
    float4 r4 = ((const float4*)(resid + (size_t)node * HH))[c4];

    const bool bn = (stats != nullptr);
    float4 sc = {1.f, 1.f, 1.f, 1.f}, sh = {0.f, 0.f, 0.f, 0.f};
    if (bn) {
        const float invN = 1.f / (float)NN;
        float4 s  = ((const float4*)stats)[c4];
        float4 s2 = ((const float4*)(stats + 128))[c4];
        float4 g  = ((const float4*)gamma)[c4];
        float4 b  = ((const float4*)beta)[c4];
        float m, var;
        m = s.x * invN; var = s2.x * invN - m * m;
        sc.x = rsqrtf(var + EPS_C) * g.x; sh.x = b.x - m * sc.x;
        m = s.y * invN; var = s2.y * invN - m * m;
        sc.y = rsqrtf(var + EPS_C) * g.y; sh.y = b.y - m * sc.y;
        m = s.z * invN; var = s2.z * invN - m * m;
        sc.z = rsqrtf(var + EPS_C) * g.z; sh.z = b.z - m * sc.z;
        m = s.w * invN; var = s2.w * invN - m * m;
        sc.w = rsqrtf(var + EPS_C) * g.w; sh.w = b.w - m * sc.w;
    }

    int e1 = row_ptr[node + 1];
    int e = row_ptr[node] + half;
    float4 acc = {0.f, 0.f, 0.f, 0.f};
    float4 acc2 = {0.f, 0.f, 0.f, 0.f};
    for (; e + 2 < e1; e += 4) {
        int s0 = sorted_src[e];
        int s1 = sorted_src[e + 2];
        float4 v0 = ((const float4*)(z + (size_t)s0 * HH))[c4];
        float4 v1 = ((const float4*)(z + (size_t)s1 * HH))[c4];
        if (bn) {
            v0.x = fmaxf(0.f, v0.x * sc.x + sh.x);
            v0.y = fmaxf(0.f, v0.y * sc.y + sh.y);
            v0.z = fmaxf(0.f, v0.z * sc.z + sh.z);
            v0.w = fmaxf(0.f, v0.w * sc.w + sh.w);
            v1.x = fmaxf(0.f, v1.x * sc.x + sh.x);
            v1.y = fmaxf(0.f, v1.y * sc.y + sh.y);
            v1.z = fmaxf(0.f, v1.z * sc.z + sh.z);
            v1.w = fmaxf(0.f, v1.w * sc.w + sh.w);
        }
        acc.x += v0.x; acc.y += v0.y; acc.z += v0.z; acc.w += v0.w;
        acc2.x += v1.x; acc2.y += v1.y; acc2.z += v1.z; acc2.w += v1.w;
    }
    if (e < e1) {
        int s = sorted_src[e];
        float4 v = ((const float4*)(z + (size_t)s * HH))[c4];
        if (bn) {
            v.x = fmaxf(0.f, v.x * sc.x + sh.x);
            v.y = fmaxf(0.f, v.y * sc.y + sh.y);
            v.z = fmaxf(0.f, v.z * sc.z + sh.z);
            v.w = fmaxf(0.f, v.w * sc.w + sh.w);
        }
        acc.x += v.x; acc.y += v.y; acc.z += v.z; acc.w += v.w;
    }
    acc.x += acc2.x; acc.y += acc2.y; acc.z += acc2.z; acc.w += acc2.w;
    // combine the two halves (lane i += lane i+32)
    acc.x += __shfl_down(acc.x, 32);
    acc.y += __shfl_down(acc.y, 32);
    acc.z += __shfl_down(acc.z, 32);
    acc.w += __shfl_down(acc.w, 32);
    if (half == 0) {
        const float cA = 1.f - ALPHA_C, cB = ALPHA_C;
        float4 o = {cA * acc.x + cB * r4.x, cA * acc.y + cB * r4.y,
                    cA * acc.z + cB * r4.z, cA * acc.w + cB * r4.w};
        ((float4*)(msg + (size_t)node * HH))[c4] = o;
    }
}

// ---------------------------------------------------------------------------
// Weight prep: Wp[i] = W_in (i==0) else (1-bl_i)*I + bl_i*conv_W[i-1]
__global__ __launch_bounds__(256) void prep_w(
    const float* __restrict__ W_in, const float* __restrict__ conv_W,
    float* __restrict__ Wp)
{
    int i = blockIdx.y;                          // 0..5
    int idx = blockIdx.x * 256 + threadIdx.x;    // 0..16383
    float v;
    if (i == 0) {
        v = W_in[idx];
    } else {
        float bl = logf(THETA_C / (float)i + 1.f);
        int k = idx >> 7, c = idx & 127;
        v = bl * conv_W[(size_t)(i - 1) * 16384 + idx] + ((k == c) ? (1.f - bl) : 0.f);
    }
    Wp[(size_t)i * 16384 + idx] = v;
}

// ---------------------------------------------------------------------------
// Pipelined 128-col GEMM: out = [z0|z1|z2|z3][:, :nsrc*128] @ Wp + bias.
// Round-0 tiling (TR=64 rows/block, 256 thr, 8x4/thread, stride-68 LDS) with
// the K dimension split into 64-wide stages and TWO half-size LDS buffers
// (same 34 KB total footprint -> 4 blocks/CU). Software pipeline:
//   stage s: compute buf[s&1]  ||  loads for stage s+2 already in regs;
//   then ds_write them to buf[(s+1)&1] (that buffer was last read at s-1,
//   guarded by the barrier at the end of s-1), issue loads for s+3, barrier.
// One barrier per stage; each global load gets a full compute stage (~1.5k cy)
// to land, so vmcnt never blocks in steady state. Stage s covers global
// K range [s*64, s*64+64) since sources are K-concatenated.
// nsrc=1: plain layer GEMM (2 stages). nsrc=4: JumpingKnowledge (8 stages).
// out may alias z0: each block reads only its own 64 rows and writes them at
// the very end, so there is no cross-block hazard.
// Optional fused BN-stats epilogue reduced through the dead LDS.
__global__ __launch_bounds__(256, 4) void gemm_pipe(
    const float* __restrict__ z0, const float* __restrict__ z1,
    const float* __restrict__ z2, const float* __restrict__ z3,
    int nsrc, const float* __restrict__ Wp,
    const float* __restrict__ bias, float* out,
    float* __restrict__ statsp, int nrows)
{
    __shared__ float As[2 * BUFF];   // two [64k][68] buffers, 34816 B
    const int t = threadIdx.x;
    const int tx = t & 31;           // output cols 4*tx..4*tx+3
    const int ty = t >> 5;           // rows 8*ty..8*ty+7
    const int lane = t & 63, w = t >> 6;
    const int row0 = blockIdx.x * TRG;
    const int nst = 2 * nsrc;

    // staging geometry: 4 float4 per thread per stage
    const int sr  = lane & 15;               // + i*16 -> row
    const int sk4 = w * 4 + (lane >> 4);     // local f4 col 0..15

    float4 r[4];

    auto LD = [&](int s) {                   // issue stage-s global loads
        int j = s >> 1, h = s & 1;
        const float* Z = z0;
        if (j == 1) Z = z1; else if (j == 2) Z = z2; else if (j == 3) Z = z3;
        const float4* Z4 = (const float4*)Z;
#pragma unroll
        for (int i = 0; i < 4; ++i) {
            int rr = i * 16 + sr;
            float4 v = {0.f, 0.f, 0.f, 0.f};
            if (row0 + rr < nrows)
                v = Z4[(size_t)(row0 + rr) * 32 + h * 16 + sk4];
            r[i] = v;
        }
    };
    auto ST = [&](int b) {                   // regs -> LDS buffer b (transposed)
        float* B = As + b * BUFF;
        int k = sk4 * 4;
#pragma unroll
        for (int i = 0; i < 4; ++i) {
            int rr = i * 16 + sr;
            B[(k + 0) * KST + rr] = r[i].x;
            B[(k + 1) * KST + rr] = r[i].y;
            B[(k + 2) * KST + rr] = r[i].z;
            B[(k + 3) * KST + rr] = r[i].w;
        }
    };

    float acc[8][4];
#pragma unroll
    for (int ii = 0; ii < 8; ++ii)
#pragma unroll
        for (int j = 0; j < 4; ++j) acc[ii][j] = 0.f;

    // prologue
    LD(0);
    ST(0);
    if (nst > 1) LD(1);
    __syncthreads();

    const float4* W4 = (const float4*)Wp;    // row k -> W4[k*32 + c4]
    const int ty8 = ty * 8;

    for (int s = 0; s < nst; ++s) {
        const float* B = As + (s & 1) * BUFF;
        const int kg0 = s * 64;              // global K offset of this stage

        float4 wc[4];
#pragma unroll
        for (int kk = 0; kk < 4; ++kk) wc[kk] = W4[(kg0 + kk) * 32 + tx];

        for (int k0 = 0; k0 < 64; k0 += 4) {
            float4 wn[4];
            const bool more = (k0 + 4 < 64);
#pragma unroll
            for (int kk = 0; kk < 4; ++kk) {
                if (more) wn[kk] = W4[(kg0 + k0 + 4 + kk) * 32 + tx];
                const float* ap = &B[(k0 + kk) * KST + ty8];
                float4 a0 = *(const float4*)ap;
                float4 a1 = *(const float4*)(ap + 4);
                float a[8] = {a0.x, a0.y, a0.z, a0.w, a1.x, a1.y, a1.z, a1.w};
                float4 ww = wc[kk];
#pragma unroll
                for (int ii = 0; ii < 8; ++ii) {
                    acc[ii][0] += a[ii] * ww.x; acc[ii][1] += a[ii] * ww.y;
                    acc[ii][2] += a[ii] * ww.z; acc[ii][3] += a[ii] * ww.w;
                }
            }
            if (more) {
#pragma unroll
                for (int kk = 0; kk < 4; ++kk) wc[kk] = wn[kk];
            }
        }

        if (s + 1 < nst) {
            ST((s + 1) & 1);                 // buffer last read at stage s-1
            if (s + 2 < nst) LD(s + 2);
            __syncthreads();
        }
    }

    float4 b4 = {0.f, 0.f, 0.f, 0.f};
    if (bias) b4 = ((const float4*)bias)[tx];
    float cs[4] = {0.f, 0.f, 0.f, 0.f}, cq[4] = {0.f, 0.f, 0.f, 0.f};
    const bool doStats = (statsp != nullptr);
#pragma unroll
    for (int ii = 0; ii < 8; ++ii) {
        int rr = row0 + ty8 + ii;
        if (rr < nrows) {
            float4 v = {acc[ii][0] + b4.x, acc[ii][1] + b4.y,
                        acc[ii][2] + b4.z, acc[ii][3] + b4.w};
            ((float4*)out)[(size_t)rr * 32 + tx] = v;
            if (doStats) {
                cs[0] += v.x; cq[0] += v.x * v.x;
                cs[1] += v.y; cq[1] += v.y * v.y;
                cs[2] += v.z; cq[2] += v.z * v.z;
                cs[3] += v.w; cq[3] += v.w * v.w;
            }
        }
    }
    if (doStats) {
        __syncthreads();              // all waves done with As -> reuse as scratch
        float* red = As;              // [0..1023]=sum, [1024..2047]=sumsq
#pragma unroll
        for (int j = 0; j < 4; ++j) {
            red[ty * 128 + tx * 4 + j] = cs[j];
            red[1024 + ty * 128 + tx * 4 + j] = cq[j];
        }
        __syncthreads();
        if (t < 128) {
            float s = 0.f, q = 0.f;
#pragma unroll
            for (int g = 0; g < 8; ++g) {
                s += red[g * 128 + t];
                q += red[1024 + g * 128 + t];
            }
            atomicAdd(&statsp[t], s);
            atomicAdd(&statsp[128 + t], q);
        }
    }
}

// ---------------------------------------------------------------------------
extern "C" void kernel_launch(void* const* d_in, const int* in_sizes, int n_in,
                              void* d_out, int out_size, void* d_ws, size_t ws_size,
                              hipStream_t stream)
{
    const float* x       = (const float*)d_in[0];
    const float* W_in    = (const float*)d_in[1];
    const float* b_in    = (const float*)d_in[2];
    const float* conv_W  = (const float*)d_in[3];
    const float* bn_g    = (const float*)d_in[4];
    const float* bn_b    = (const float*)d_in[5];
    const float* W_jk    = (const float*)d_in[6];
    const float* b_jk    = (const float*)d_in[7];
    const void*  srcp    = d_in[8];
    const void*  dstp    = d_in[9];

    // Workspace: 5*NH floats (244 MiB) + stats3 + CSR (~7.3 MB) + Wp (384 KB)
    float* ws     = (float*)d_ws;
    float* x0     = ws;                        // [N,H] z0, residual
    float* msg    = ws + (size_t)NH;           // [N,H] gather target (folded)
    float* zs0    = ws + 2 * (size_t)NH;       // z per layer; zs0 reused as JK out
    float* zs1    = ws + 3 * (size_t)NH;
    float* zs2    = ws + 4 * (size_t)NH;
    float* stats3 = ws + 5 * (size_t)NH;       // [3][256] sum/sumsq per BN layer
    int*   flag       = (int*)(stats3 + 768);
    int*   hist       = flag + 1;              // [NN]
    int*   incl       = hist + NN;             // [NN]
    int*   row_ptr    = incl + NN;             // [NN+1]
    int*   cursor     = row_ptr + NN + 1;      // [NN]
    int*   bsum       = cursor + NN;           // [NBLK]
    int*   sorted_src = bsum + NBLK + 1;       // [EE]
    float* Wp         = (float*)(sorted_src + EE);  // [6][128][128]

    const int GEMM_GRID = (NN + TRG - 1) / TRG;   // 1563
    const int EDGE_GRID = (EE + 255) / 256;       // 6250
    const int NODE_GRID = (NN + 3) / 4;           // 25000

    // ---- CSR build + weight prep + stats zero (once per launch) ----
    detect_idx64<<<1, 1, 0, stream>>>((const int*)srcp, flag);
    zero_int_k<<<(NN + 255) / 256, 256, 0, stream>>>(hist, NN);
    zero_f4_k<<<1, 192, 0, stream>>>((float4*)stats3, 192);
    hist_k<<<EDGE_GRID, 256, 0, stream>>>(dstp, flag, hist);
    scan1_k<<<NBLK, SCAN_B, 0, stream>>>(hist, incl, bsum);
    scan2_k<<<1, 512, 0, stream>>>(bsum);
    scan3_k<<<NBLK, SCAN_B, 0, stream>>>(hist, incl, bsum, row_ptr, cursor);
    fill_k<<<EDGE_GRID, 256, 0, stream>>>(srcp, dstp, flag, cursor, sorted_src);
    prep_w<<<dim3(64, 6), 256, 0, stream>>>(W_in, conv_W, Wp);

    // ---- x0 = x @ W_in + b_in ----
    gemm_pipe<<<GEMM_GRID, 256, 0, stream>>>(x, x, x, x, 1, Wp, b_in, x0,
                                             nullptr, NN);

    const float* act = x0;
    const float* stats_cur = nullptr;   // BN stats for act (null = no BN)
    const float* g_cur = nullptr;
    const float* b_cur = nullptr;

    for (int i = 0; i < 5; ++i) {
        // msg = (1-alpha)*segment_sum(act[src]) + alpha*x0   (BN fused on load)
        gather_k<<<NODE_GRID, 256, 0, stream>>>(act, row_ptr, sorted_src,
                                                stats_cur, g_cur, b_cur, x0, msg);

        float* zraw = (i >= 3) ? (float*)d_out : (zs0 + (size_t)i * NH);
        float* stats_next = (i < 3) ? (stats3 + (size_t)i * 256) : nullptr;
        gemm_pipe<<<GEMM_GRID, 256, 0, stream>>>(msg, msg, msg, msg, 1,
                                                 Wp + (size_t)(i + 1) * 16384,
                                                 nullptr, zraw, stats_next, NN);
        if (i < 3) {
            act = zraw;                 // BN+ReLU fused into next gather
            stats_cur = stats_next;
            g_cur = bn_g + (size_t)i * HH;
            b_cur = bn_b + (size_t)i * HH;
        } else if (i == 3) {
            gemm_pipe<<<GEMM_GRID, 256, 0, stream>>>(zs0, zs1, zs2,
                                                     (const float*)d_out, 4,
                                                     W_jk, b_jk, zs0, nullptr, NN);
            act = zs0;
            stats_cur = nullptr;
            g_cur = nullptr;
            b_cur = nullptr;
        }
    }
}

// Round 4
// 11505.131 us; speedup vs baseline: 1.0116x; 1.0116x over previous
//
#include <hip/hip_runtime.h>
#include <hip/hip_bf16.h>
#include <cmath>
#include <cstddef>

// Problem constants (from reference)
#define NN 100000
#define HH 128
#define EE 1600000
#define NH (NN * HH)
#define ALPHA_C 0.1f
#define THETA_C 0.5f
#define EPS_C 1e-5f

constexpr int TRG = 64;        // rows per GEMM block
constexpr int KST = 68;        // LDS stride (floats): b128-aligned, 2-way max
constexpr int BUFF = 64 * KST; // floats per K-stage buffer (4352)
constexpr int SCAN_B = 256;
constexpr int NBLK = (NN + SCAN_B - 1) / SCAN_B;   // 391 scan blocks

// ---------------------------------------------------------------------------
__global__ __launch_bounds__(256) void zero_int_k(int* __restrict__ p, int n) {
    int i = blockIdx.x * 256 + threadIdx.x;
    if (i < n) p[i] = 0;
}
__global__ __launch_bounds__(256) void zero_f4_k(float4* __restrict__ p, int n4) {
    int i = blockIdx.x * 256 + threadIdx.x;
    if (i < n4) p[i] = float4{0.f, 0.f, 0.f, 0.f};
}

// ---------------------------------------------------------------------------
// Index dtype detection: int64 (values < 2^31) -> every odd 32-bit word is 0.
__global__ void detect_idx64(const int* __restrict__ p, int* __restrict__ flag) {
    int any = 0;
    for (int i = 0; i < 64; ++i) any |= p[2 * i + 1];
    *flag = (any == 0) ? 1 : 0;
}

__device__ __forceinline__ int load_idx(const void* p, int e, int is64) {
    return is64 ? (int)((const long long*)p)[e] : ((const int*)p)[e];
}

// ---------------------------------------------------------------------------
// CSR build: histogram of dst
__global__ __launch_bounds__(256) void hist_k(
    const void* __restrict__ dstp, const int* __restrict__ flag,
    int* __restrict__ hist)
{
    int e = blockIdx.x * 256 + threadIdx.x;
    if (e >= EE) return;
    atomicAdd(&hist[load_idx(dstp, e, *flag)], 1);
}

__global__ __launch_bounds__(SCAN_B) void scan1_k(
    const int* __restrict__ hist, int* __restrict__ incl, int* __restrict__ bsum)
{
    __shared__ int sh[SCAN_B];
    int t = threadIdx.x;
    int i = blockIdx.x * SCAN_B + t;
    int v = (i < NN) ? hist[i] : 0;
    sh[t] = v;
    __syncthreads();
    for (int off = 1; off < SCAN_B; off <<= 1) {
        int x = (t >= off) ? sh[t - off] : 0;
        __syncthreads();
        sh[t] += x;
        __syncthreads();
    }
    if (i < NN) incl[i] = sh[t];
    if (t == SCAN_B - 1) bsum[blockIdx.x] = sh[t];
}

__global__ __launch_bounds__(512) void scan2_k(int* __restrict__ bsum) {
    __shared__ int sh[512];
    int t = threadIdx.x;
    sh[t] = (t < NBLK) ? bsum[t] : 0;
    __syncthreads();
    for (int off = 1; off < 512; off <<= 1) {
        int x = (t >= off) ? sh[t - off] : 0;
        __syncthreads();
        sh[t] += x;
        __syncthreads();
    }
    if (t < NBLK) bsum[t] = sh[t];
}

__global__ __launch_bounds__(SCAN_B) void scan3_k(
    const int* __restrict__ hist, const int* __restrict__ incl,
    const int* __restrict__ bsum, int* __restrict__ row_ptr,
    int* __restrict__ cursor)
{
    int b = blockIdx.x;
    int i = b * SCAN_B + threadIdx.x;
    if (i < NN) {
        int ex = incl[i] - hist[i] + (b > 0 ? bsum[b - 1] : 0);
        row_ptr[i] = ex;
        cursor[i] = ex;
    }
    if (i == 0) row_ptr[NN] = EE;
}

__global__ __launch_bounds__(256) void fill_k(
    const void* __restrict__ srcp, const void* __restrict__ dstp,
    const int* __restrict__ flag, int* __restrict__ cursor,
    int* __restrict__ sorted_src)
{
    int e = blockIdx.x * 256 + threadIdx.x;
    if (e >= EE) return;
    int is64 = *flag;
    int d = load_idx(dstp, e, is64);
    int pos = atomicAdd(&cursor[d], 1);
    sorted_src[pos] = load_idx(srcp, e, is64);
}

// ---------------------------------------------------------------------------
// CSR gather + residual fold: msg[n] = (1-ALPHA)*sum_{e in n}(act(z[src]))
//                                       + ALPHA*x0[n]
// act = BN+ReLU derived in-register from raw sum/sumsq stats when stats!=null.
// 4 edges in flight per wave. (Verified passing rounds 2-3.)
__global__ __launch_bounds__(256) void gather_k(
    const float* __restrict__ z, const int* __restrict__ row_ptr,
    const int* __restrict__ sorted_src,
    const float* __restrict__ stats,    // [256]: sum, sumsq; null = no BN
    const float* __restrict__ gamma, const float* __restrict__ beta,
    const float* __restrict__ resid,    // x0
    float* __restrict__ msg)
{
    int node = blockIdx.x * 4 + (threadIdx.x >> 6);
    if (node >= NN) return;
    int lane = threadIdx.x & 63;
    int half = lane >> 5;        // which edge stream of the pair
    int c4 = lane & 31;          // float4 column index

    float4 r4 = ((const float4*)(resid + (size_t)node * HH))[c4];

    const bool bn = (stats != nullptr);
    float4 sc = {1.f, 1.f, 1.f, 1.f}, sh = {0.f, 0.f, 0.f, 0.f};
    if (bn) {
        const float invN = 1.f / (float)NN;
        float4 s  = ((const float4*)stats)[c4];
        float4 s2 = ((const float4*)(stats + 128))[c4];
        float4 g  = ((const float4*)gamma)[c4];
        float4 b  = ((const float4*)beta)[c4];
        float m, var;
        m = s.x * invN; var = s2.x * invN - m * m;
        sc.x = rsqrtf(var + EPS_C) * g.x; sh.x = b.x - m * sc.x;
        m = s.y * invN; var = s2.y * invN - m * m;
        sc.y = rsqrtf(var + EPS_C) * g.y; sh.y = b.y - m * sc.y;
        m = s.z * invN; var = s2.z * invN - m * m;
        sc.z = rsqrtf(var + EPS_C) * g.z; sh.z = b.z - m * sc.z;
        m = s.w * invN; var = s2.w * invN - m * m;
        sc.w = rsqrtf(var + EPS_C) * g.w; sh.w = b.w - m * sc.w;
    }

    int e1 = row_ptr[node + 1];
    int e = row_ptr[node] + half;
    float4 acc = {0.f, 0.f, 0.f, 0.f};
    float4 acc2 = {0.f, 0.f, 0.f, 0.f};
    for (; e + 2 < e1; e += 4) {
        int s0 = sorted_src[e];
        int s1 = sorted_src[e + 2];
        float4 v0 = ((const float4*)(z + (size_t)s0 * HH))[c4];
        float4 v1 = ((const float4*)(z + (size_t)s1 * HH))[c4];
        if (bn) {
            v0.x = fmaxf(0.f, v0.x * sc.x + sh.x);
            v0.y = fmaxf(0.f, v0.y * sc.y + sh.y);
            v0.z = fmaxf(0.f, v0.z * sc.z + sh.z);
            v0.w = fmaxf(0.f, v0.w * sc.w + sh.w);
            v1.x = fmaxf(0.f, v1.x * sc.x + sh.x);
            v1.y = fmaxf(0.f, v1.y * sc.y + sh.y);
            v1.z = fmaxf(0.f, v1.z * sc.z + sh.z);
            v1.w = fmaxf(0.f, v1.w * sc.w + sh.w);
        }
        acc.x += v0.x; acc.y += v0.y; acc.z += v0.z; acc.w += v0.w;
        acc2.x += v1.x; acc2.y += v1.y; acc2.z += v1.z; acc2.w += v1.w;
    }
    if (e < e1) {
        int s = sorted_src[e];
        float4 v = ((const float4*)(z + (size_t)s * HH))[c4];
        if (bn) {
            v.x = fmaxf(0.f, v.x * sc.x + sh.x);
            v.y = fmaxf(0.f, v.y * sc.y + sh.y);
            v.z = fmaxf(0.f, v.z * sc.z + sh.z);
            v.w = fmaxf(0.f, v.w * sc.w + sh.w);
        }
        acc.x += v.x; acc.y += v.y; acc.z += v.z; acc.w += v.w;
    }
    acc.x += acc2.x; acc.y += acc2.y; acc.z += acc2.z; acc.w += acc2.w;
    acc.x += __shfl_down(acc.x, 32);
    acc.y += __shfl_down(acc.y, 32);
    acc.z += __shfl_down(acc.z, 32);
    acc.w += __shfl_down(acc.w, 32);
    if (half == 0) {
        const float cA = 1.f - ALPHA_C, cB = ALPHA_C;
        float4 o = {cA * acc.x + cB * r4.x, cA * acc.y + cB * r4.y,
                    cA * acc.z + cB * r4.z, cA * acc.w + cB * r4.w};
        ((float4*)(msg + (size_t)node * HH))[c4] = o;
    }
}

// ---------------------------------------------------------------------------
// Weight prep: Wp[i] = W_in (i==0) else (1-bl_i)*I + bl_i*conv_W[i-1]
__global__ __launch_bounds__(256) void prep_w(
    const float* __restrict__ W_in, const float* __restrict__ conv_W,
    float* __restrict__ Wp)
{
    int i = blockIdx.y;                          // 0..5
    int idx = blockIdx.x * 256 + threadIdx.x;    // 0..16383
    float v;
    if (i == 0) {
        v = W_in[idx];
    } else {
        float bl = logf(THETA_C / (float)i + 1.f);
        int k = idx >> 7, c = idx & 127;
        v = bl * conv_W[(size_t)(i - 1) * 16384 + idx] + ((k == c) ? (1.f - bl) : 0.f);
    }
    Wp[(size_t)i * 16384 + idx] = v;
}

// ---------------------------------------------------------------------------
// Pipelined 128-col GEMM: out = [z0|z1|z2|z3][:, :nsrc*128] @ Wp + bias.
// Round-0 tiling (64 rows/block, 256 thr, 8x4/thread, stride-68 LDS), K split
// into 64-wide stages ping-ponging two half buffers (34 KB total, 4 blk/CU).
// Loads for stage s+2 are issued during compute of stage s, so the vmcnt wait
// before the ds_write is covered by a full compute stage. One barrier/stage.
// CODEGEN NOTE: no lambdas anywhere -- round 3's [&]-captures escaped the
// stack frame, SROA failed, and acc[][] went to scratch (14 GB/dispatch of
// scratch traffic, 2.4% VALUBusy). Macros + named staging regs r0..r3 keep
// every array register-allocated (round-0 inner loop copied verbatim).
// out may alias z0: each block reads only its own 64 rows (epilogue-write).
// Optional fused BN-stats epilogue reduced through the dead LDS.

#define LD_STAGE(s_)                                                          \
    {                                                                         \
        const int j_ = (s_) >> 1, h_ = (s_) & 1;                              \
        const float* Zp_ = (j_ == 0) ? z0 : (j_ == 1) ? z1                    \
                          : (j_ == 2) ? z2 : z3;                              \
        const float4* Z4_ = (const float4*)Zp_;                               \
        const int cb_ = h_ * 16 + sk4;                                        \
        r0 = float4{0.f, 0.f, 0.f, 0.f}; r1 = r0; r2 = r0; r3 = r0;           \
        if (row0 + sr      < nrows) r0 = Z4_[(size_t)(row0 + sr)      * 32 + cb_]; \
        if (row0 + sr + 16 < nrows) r1 = Z4_[(size_t)(row0 + sr + 16) * 32 + cb_]; \
        if (row0 + sr + 32 < nrows) r2 = Z4_[(size_t)(row0 + sr + 32) * 32 + cb_]; \
        if (row0 + sr + 48 < nrows) r3 = Z4_[(size_t)(row0 + sr + 48) * 32 + cb_]; \
    }

#define ST_STAGE(b_)                                                          \
    {                                                                         \
        float* B_ = As + (b_) * BUFF;                                         \
        const int k_ = sk4 * 4;                                               \
        B_[(k_ + 0) * KST + sr] = r0.x;  B_[(k_ + 1) * KST + sr] = r0.y;      \
        B_[(k_ + 2) * KST + sr] = r0.z;  B_[(k_ + 3) * KST + sr] = r0.w;      \
        B_[(k_ + 0) * KST + sr + 16] = r1.x; B_[(k_ + 1) * KST + sr + 16] = r1.y; \
        B_[(k_ + 2) * KST + sr + 16] = r1.z; B_[(k_ + 3) * KST + sr + 16] = r1.w; \
        B_[(k_ + 0) * KST + sr + 32] = r2.x; B_[(k_ + 1) * KST + sr + 32] = r2.y; \
        B_[(k_ + 2) * KST + sr + 32] = r2.z; B_[(k_ + 3) * KST + sr + 32] = r2.w; \
        B_[(k_ + 0) * KST + sr + 48] = r3.x; B_[(k_ + 1) * KST + sr + 48] = r3.y; \
        B_[(k_ + 2) * KST + sr + 48] = r3.z; B_[(k_ + 3) * KST + sr + 48] = r3.w; \
    }

__global__ __launch_bounds__(256, 4) void gemm_pipe(
    const float* __restrict__ z0, const float* __restrict__ z1,
    const float* __restrict__ z2, const float* __restrict__ z3,
    int nsrc, const float* __restrict__ Wp,
    const float* __restrict__ bias, float* out,
    float* __restrict__ statsp, int nrows)
{
    __shared__ float As[2 * BUFF];   // two [64k][68] buffers, 34816 B
    const int t = threadIdx.x;
    const int tx = t & 31;           // output cols 4*tx..4*tx+3
    const int ty = t >> 5;           // rows 8*ty..8*ty+7
    const int lane = t & 63, w = t >> 6;
    const int row0 = blockIdx.x * TRG;
    const int nst = 2 * nsrc;

    // staging geometry: rows {sr, sr+16, sr+32, sr+48}, f4-col sk4 (0..15)
    const int sr  = lane & 15;
    const int sk4 = w * 4 + (lane >> 4);

    float4 r0, r1, r2, r3;           // named staging registers (no arrays)

    float acc[8][4];
#pragma unroll
    for (int ii = 0; ii < 8; ++ii)
#pragma unroll
        for (int j = 0; j < 4; ++j) acc[ii][j] = 0.f;

    // prologue
    LD_STAGE(0);
    ST_STAGE(0);
    if (nst > 1) LD_STAGE(1);
    __syncthreads();

    const float4* W4 = (const float4*)Wp;    // row k -> W4[k*32 + c4]
    const int ty8 = ty * 8;

    for (int s = 0; s < nst; ++s) {
        const float* B = As + (s & 1) * BUFF;
        const int kg0 = s * 64;              // global K offset of this stage

        float4 wc[4];
#pragma unroll
        for (int kk = 0; kk < 4; ++kk) wc[kk] = W4[(kg0 + kk) * 32 + tx];

        for (int k0 = 0; k0 < 64; k0 += 4) {
            float4 wn[4];
            const bool more = (k0 + 4 < 64);
#pragma unroll
            for (int kk = 0; kk < 4; ++kk) {
                if (more) wn[kk] = W4[(kg0 + k0 + 4 + kk) * 32 + tx];
                const float* ap = &B[(k0 + kk) * KST + ty8];
                float4 a0 = *(const float4*)ap;
                float4 a1 = *(const float4*)(ap + 4);
                float a[8] = {a0.x, a0.y, a0.z, a0.w, a1.x, a1.y, a1.z, a1.w};
                float4 ww = wc[kk];
#pragma unroll
                for (int ii = 0; ii < 8; ++ii) {
                    acc[ii][0] += a[ii] * ww.x; acc[ii][1] += a[ii] * ww.y;
                    acc[ii][2] += a[ii] * ww.z; acc[ii][3] += a[ii] * ww.w;
                }
            }
            if (more) {
#pragma unroll
                for (int kk = 0; kk < 4; ++kk) wc[kk] = wn[kk];
            }
        }

        if (s + 1 < nst) {
            ST_STAGE((s + 1) & 1);           // buffer last read at stage s-1
            if (s + 2 < nst) LD_STAGE(s + 2);
            __syncthreads();
        }
    }

    float4 b4 = {0.f, 0.f, 0.f, 0.f};
    if (bias) b4 = ((const float4*)bias)[tx];
    float cs[4] = {0.f, 0.f, 0.f, 0.f}, cq[4] = {0.f, 0.f, 0.f, 0.f};
    const bool doStats = (statsp != nullptr);
#pragma unroll
    for (int ii = 0; ii < 8; ++ii) {
        int rr = row0 + ty8 + ii;
        if (rr < nrows) {
            float4 v = {acc[ii][0] + b4.x, acc[ii][1] + b4.y,
                        acc[ii][2] + b4.z, acc[ii][3] + b4.w};
            ((float4*)out)[(size_t)rr * 32 + tx] = v;
            if (doStats) {
                cs[0] += v.x; cq[0] += v.x * v.x;
                cs[1] += v.y; cq[1] += v.y * v.y;
                cs[2] += v.z; cq[2] += v.z * v.z;
                cs[3] += v.w; cq[3] += v.w * v.w;
            }
        }
    }
    if (doStats) {
        __syncthreads();              // all waves done with As -> reuse as scratch
        float* red = As;              // [0..1023]=sum, [1024..2047]=sumsq
#pragma unroll
        for (int j = 0; j < 4; ++j) {
            red[ty * 128 + tx * 4 + j] = cs[j];
            red[1024 + ty * 128 + tx * 4 + j] = cq[j];
        }
        __syncthreads();
        if (t < 128) {
            float s = 0.f, q = 0.f;
#pragma unroll
            for (int g = 0; g < 8; ++g) {
                s += red[g * 128 + t];
                q += red[1024 + g * 128 + t];
            }
            atomicAdd(&statsp[t], s);
            atomicAdd(&statsp[128 + t], q);
        }
    }
}

// ---------------------------------------------------------------------------
extern "C" void kernel_launch(void* const* d_in, const int* in_sizes, int n_in,
                              void* d_out, int out_size, void* d_ws, size_t ws_size,
                              hipStream_t stream)
{
    const float* x       = (const float*)d_in[0];
    const float* W_in    = (const float*)d_in[1];
    const float* b_in    = (const float*)d_in[2];
    const float* conv_W  = (const float*)d_in[3];
    const float* bn_g    = (const float*)d_in[4];
    const float* bn_b    = (const float*)d_in[5];
    const float* W_jk    = (const float*)d_in[6];
    const float* b_jk    = (const float*)d_in[7];
    const void*  srcp    = d_in[8];
    const void*  dstp    = d_in[9];

    // Workspace: 5*NH floats (244 MiB) + stats3 + CSR (~7.3 MB) + Wp (384 KB)
    float* ws     = (float*)d_ws;
    float* x0     = ws;                        // [N,H] z0, residual
    float* msg    = ws + (size_t)NH;           // [N,H] gather target (folded)
    float* zs0    = ws + 2 * (size_t)NH;       // z per layer; zs0 reused as JK out
    float* zs1    = ws + 3 * (size_t)NH;
    float* zs2    = ws + 4 * (size_t)NH;
    float* stats3 = ws + 5 * (size_t)NH;       // [3][256] sum/sumsq per BN layer
    int*   flag       = (int*)(stats3 + 768);
    int*   hist       = flag + 1;              // [NN]
    int*   incl       = hist + NN;             // [NN]
    int*   row_ptr    = incl + NN;             // [NN+1]
    int*   cursor     = row_ptr + NN + 1;      // [NN]
    int*   bsum       = cursor + NN;           // [NBLK]
    int*   sorted_src = bsum + NBLK + 1;       // [EE]
    float* Wp         = (float*)(sorted_src + EE);  // [6][128][128]

    const int GEMM_GRID = (NN + TRG - 1) / TRG;   // 1563
    const int EDGE_GRID = (EE + 255) / 256;       // 6250
    const int NODE_GRID = (NN + 3) / 4;           // 25000

    // ---- CSR build + weight prep + stats zero (once per launch) ----
    detect_idx64<<<1, 1, 0, stream>>>((const int*)srcp, flag);
    zero_int_k<<<(NN + 255) / 256, 256, 0, stream>>>(hist, NN);
    zero_f4_k<<<1, 192, 0, stream>>>((float4*)stats3, 192);
    hist_k<<<EDGE_GRID, 256, 0, stream>>>(dstp, flag, hist);
    scan1_k<<<NBLK, SCAN_B, 0, stream>>>(hist, incl, bsum);
    scan2_k<<<1, 512, 0, stream>>>(bsum);
    scan3_k<<<NBLK, SCAN_B, 0, stream>>>(hist, incl, bsum, row_ptr, cursor);
    fill_k<<<EDGE_GRID, 256, 0, stream>>>(srcp, dstp, flag, cursor, sorted_src);
    prep_w<<<dim3(64, 6), 256, 0, stream>>>(W_in, conv_W, Wp);

    // ---- x0 = x @ W_in + b_in ----
    gemm_pipe<<<GEMM_GRID, 256, 0, stream>>>(x, x, x, x, 1, Wp, b_in, x0,
                                             nullptr, NN);

    const float* act = x0;
    const float* stats_cur = nullptr;   // BN stats for act (null = no BN)
    const float* g_cur = nullptr;
    const float* b_cur = nullptr;

    for (int i = 0; i < 5; ++i) {
        // msg = (1-alpha)*segment_sum(act[src]) + alpha*x0   (BN fused on load)
        gather_k<<<NODE_GRID, 256, 0, stream>>>(act, row_ptr, sorted_src,
                                                stats_cur, g_cur, b_cur, x0, msg);

        float* zraw = (i >= 3) ? (float*)d_out : (zs0 + (size_t)i * NH);
        float* stats_next = (i < 3) ? (stats3 + (size_t)i * 256) : nullptr;
        gemm_pipe<<<GEMM_GRID, 256, 0, stream>>>(msg, msg, msg, msg, 1,
                                                 Wp + (size_t)(i + 1) * 16384,
                                                 nullptr, zraw, stats_next, NN);
        if (i < 3) {
            act = zraw;                 // BN+ReLU fused into next gather
            stats_cur = stats_next;
            g_cur = bn_g + (size_t)i * HH;
            b_cur = bn_b + (size_t)i * HH;
        } else if (i == 3) {
            gemm_pipe<<<GEMM_GRID, 256, 0, stream>>>(zs0, zs1, zs2,
                                                     (const float*)d_out, 4,
                                                     W_jk, b_jk, zs0, nullptr, NN);
            act = zs0;
            stats_cur = nullptr;
            g_cur = nullptr;
            b_cur = nullptr;
        }
    }
}

// Round 5
// 1528.242 us; speedup vs baseline: 7.6154x; 7.5283x over previous
//
#include <hip/hip_runtime.h>
#include <hip/hip_bf16.h>
#include <cmath>
#include <cstddef>

// Problem constants (from reference)
#define NN 100000
#define HH 128
#define EE 1600000
#define NH (NN * HH)
#define ALPHA_C 0.1f
#define THETA_C 0.5f
#define EPS_C 1e-5f

constexpr int TR = 64;    // rows per GEMM block
constexpr int AST = 68;   // LDS A^T stride (floats): 16B-aligned rows, b128-clean
constexpr int SCAN_B = 256;
constexpr int NBLK = (NN + SCAN_B - 1) / SCAN_B;   // 391 scan blocks

// ---------------------------------------------------------------------------
__global__ __launch_bounds__(256) void zero_int_k(int* __restrict__ p, int n) {
    int i = blockIdx.x * 256 + threadIdx.x;
    if (i < n) p[i] = 0;
}
__global__ __launch_bounds__(256) void zero_f4_k(float4* __restrict__ p, int n4) {
    int i = blockIdx.x * 256 + threadIdx.x;
    if (i < n4) p[i] = float4{0.f, 0.f, 0.f, 0.f};
}

// ---------------------------------------------------------------------------
// Index dtype detection: int64 (values < 2^31) -> every odd 32-bit word is 0.
__global__ void detect_idx64(const int* __restrict__ p, int* __restrict__ flag) {
    int any = 0;
    for (int i = 0; i < 64; ++i) any |= p[2 * i + 1];
    *flag = (any == 0) ? 1 : 0;
}

__device__ __forceinline__ int load_idx(const void* p, int e, int is64) {
    return is64 ? (int)((const long long*)p)[e] : ((const int*)p)[e];
}

// ---------------------------------------------------------------------------
// CSR build: histogram of dst
__global__ __launch_bounds__(256) void hist_k(
    const void* __restrict__ dstp, const int* __restrict__ flag,
    int* __restrict__ hist)
{
    int e = blockIdx.x * 256 + threadIdx.x;
    if (e >= EE) return;
    atomicAdd(&hist[load_idx(dstp, e, *flag)], 1);
}

__global__ __launch_bounds__(SCAN_B) void scan1_k(
    const int* __restrict__ hist, int* __restrict__ incl, int* __restrict__ bsum)
{
    __shared__ int sh[SCAN_B];
    int t = threadIdx.x;
    int i = blockIdx.x * SCAN_B + t;
    int v = (i < NN) ? hist[i] : 0;
    sh[t] = v;
    __syncthreads();
    for (int off = 1; off < SCAN_B; off <<= 1) {
        int x = (t >= off) ? sh[t - off] : 0;
        __syncthreads();
        sh[t] += x;
        __syncthreads();
    }
    if (i < NN) incl[i] = sh[t];
    if (t == SCAN_B - 1) bsum[blockIdx.x] = sh[t];
}

__global__ __launch_bounds__(512) void scan2_k(int* __restrict__ bsum) {
    __shared__ int sh[512];
    int t = threadIdx.x;
    sh[t] = (t < NBLK) ? bsum[t] : 0;
    __syncthreads();
    for (int off = 1; off < 512; off <<= 1) {
        int x = (t >= off) ? sh[t - off] : 0;
        __syncthreads();
        sh[t] += x;
        __syncthreads();
    }
    if (t < NBLK) bsum[t] = sh[t];
}

__global__ __launch_bounds__(SCAN_B) void scan3_k(
    const int* __restrict__ hist, const int* __restrict__ incl,
    const int* __restrict__ bsum, int* __restrict__ row_ptr,
    int* __restrict__ cursor)
{
    int b = blockIdx.x;
    int i = b * SCAN_B + threadIdx.x;
    if (i < NN) {
        int ex = incl[i] - hist[i] + (b > 0 ? bsum[b - 1] : 0);
        row_ptr[i] = ex;
        cursor[i] = ex;
    }
    if (i == 0) row_ptr[NN] = EE;
}

__global__ __launch_bounds__(256) void fill_k(
    const void* __restrict__ srcp, const void* __restrict__ dstp,
    const int* __restrict__ flag, int* __restrict__ cursor,
    int* __restrict__ sorted_src)
{
    int e = blockIdx.x * 256 + threadIdx.x;
    if (e >= EE) return;
    int is64 = *flag;
    int d = load_idx(dstp, e, is64);
    int pos = atomicAdd(&cursor[d], 1);
    sorted_src[pos] = load_idx(srcp, e, is64);
}

// ---------------------------------------------------------------------------
// CSR gather + residual fold: msg[n] = (1-ALPHA)*sum_{e in n}(act(z[src]))
//                                       + ALPHA*x0[n]
// act = BN+ReLU derived in-register from raw sum/sumsq stats when stats!=null.
// 4 edges in flight per wave (half-split x 2-deep unroll) for MLP.
// (This exact kernel passed the harness in rounds 2, 3 and 4.)
__global__ __launch_bounds__(256) void gather_k(
    const float* __restrict__ z, const int* __restrict__ row_ptr,
    const int* __restrict__ sorted_src,
    const float* __restrict__ stats,    // [256]: sum, sumsq; null = no BN
    const float* __restrict__ gamma, const float* __restrict__ beta,
    const float* __restrict__ resid,    // x0
    float* __restrict__ msg)
{
    int node = blockIdx.x * 4 + (threadIdx.x >> 6);
    if (node >= NN) return;
    int lane = threadIdx.x & 63;
    int half = lane >> 5;        // which edge stream of the pair
    int c4 = lane & 31;          // float4 column index

    float4 r4 = ((const float4*)(resid + (size_t)node * HH))[c4];

    const bool bn = (stats != nullptr);
    float4 sc = {1.f, 1.f, 1.f, 1.f}, sh = {0.f, 0.f, 0.f, 0.f};
    if (bn) {
        const float invN = 1.f / (float)NN;
        float4 s  = ((const float4*)stats)[c4];
        float4 s2 = ((const float4*)(stats + 128))[c4];
        float4 g  = ((const float4*)gamma)[c4];
        float4 b  = ((const float4*)beta)[c4];
        float m, var;
        m = s.x * invN; var = s2.x * invN - m * m;
        sc.x = rsqrtf(var + EPS_C) * g.x; sh.x = b.x - m * sc.x;
        m = s.y * invN; var = s2.y * invN - m * m;
        sc.y = rsqrtf(var + EPS_C) * g.y; sh.y = b.y - m * sc.y;
        m = s.z * invN; var = s2.z * invN - m * m;
        sc.z = rsqrtf(var + EPS_C) * g.z; sh.z = b.z - m * sc.z;
        m = s.w * invN; var = s2.w * invN - m * m;
        sc.w = rsqrtf(var + EPS_C) * g.w; sh.w = b.w - m * sc.w;
    }

    int e1 = row_ptr[node + 1];
    int e = row_ptr[node] + half;
    float4 acc = {0.f, 0.f, 0.f, 0.f};
    float4 acc2 = {0.f, 0.f, 0.f, 0.f};
    for (; e + 2 < e1; e += 4) {
        int s0 = sorted_src[e];
        int s1 = sorted_src[e + 2];
        float4 v0 = ((const float4*)(z + (size_t)s0 * HH))[c4];
        float4 v1 = ((const float4*)(z + (size_t)s1 * HH))[c4];
        if (bn) {
            v0.x = fmaxf(0.f, v0.x * sc.x + sh.x);
            v0.y = fmaxf(0.f, v0.y * sc.y + sh.y);
            v0.z = fmaxf(0.f, v0.z * sc.z + sh.z);
            v0.w = fmaxf(0.f, v0.w * sc.w + sh.w);
            v1.x = fmaxf(0.f, v1.x * sc.x + sh.x);
            v1.y = fmaxf(0.f, v1.y * sc.y + sh.y);
            v1.z = fmaxf(0.f, v1.z * sc.z + sh.z);
            v1.w = fmaxf(0.f, v1.w * sc.w + sh.w);
        }
        acc.x += v0.x; acc.y += v0.y; acc.z += v0.z; acc.w += v0.w;
        acc2.x += v1.x; acc2.y += v1.y; acc2.z += v1.z; acc2.w += v1.w;
    }
    if (e < e1) {
        int s = sorted_src[e];
        float4 v = ((const float4*)(z + (size_t)s * HH))[c4];
        if (bn) {
            v.x = fmaxf(0.f, v.x * sc.x + sh.x);
            v.y = fmaxf(0.f, v.y * sc.y + sh.y);
            v.z = fmaxf(0.f, v.z * sc.z + sh.z);
            v.w = fmaxf(0.f, v.w * sc.w + sh.w);
        }
        acc.x += v.x; acc.y += v.y; acc.z += v.z; acc.w += v.w;
    }
    acc.x += acc2.x; acc.y += acc2.y; acc.z += acc2.z; acc.w += acc2.w;
    acc.x += __shfl_down(acc.x, 32);
    acc.y += __shfl_down(acc.y, 32);
    acc.z += __shfl_down(acc.z, 32);
    acc.w += __shfl_down(acc.w, 32);
    if (half == 0) {
        const float cA = 1.f - ALPHA_C, cB = ALPHA_C;
        float4 o = {cA * acc.x + cB * r4.x, cA * acc.y + cB * r4.y,
                    cA * acc.z + cB * r4.z, cA * acc.w + cB * r4.w};
        ((float4*)(msg + (size_t)node * HH))[c4] = o;
    }
}

// ---------------------------------------------------------------------------
// Weight prep: Wp[i] = W_in (i==0) else (1-bl_i)*I + bl_i*conv_W[i-1]
__global__ __launch_bounds__(256) void prep_w(
    const float* __restrict__ W_in, const float* __restrict__ conv_W,
    float* __restrict__ Wp)
{
    int i = blockIdx.y;                          // 0..5
    int idx = blockIdx.x * 256 + threadIdx.x;    // 0..16383
    float v;
    if (i == 0) {
        v = W_in[idx];
    } else {
        float bl = logf(THETA_C / (float)i + 1.f);
        int k = idx >> 7, c = idx & 127;
        v = bl * conv_W[(size_t)(i - 1) * 16384 + idx] + ((k == c) ? (1.f - bl) : 0.f);
    }
    Wp[(size_t)i * 16384 + idx] = v;
}

// ---------------------------------------------------------------------------
// 128-col GEMM, round-0 structure verbatim (TR=64, stride-68 LDS, 8x4/thread,
// 4-deep W register double-buffer, __launch_bounds__(256,4)) -- the verified
// 1592us-codegen shape. Only change vs round 0: residual second source
// (src1/cA/cB) removed, since the fold now lives in gather_k. Staging is a
// plain single-stream copy (strictly fewer instructions than verified code).
// Optional fused BN-stats epilogue reduced through the dead As LDS.
__global__ __launch_bounds__(256, 4) void gemm128(
    const float* __restrict__ A, const float* __restrict__ Wp,
    const float* __restrict__ bias, float* __restrict__ out,
    float* __restrict__ statsp, int nrows)
{
    __shared__ float As[HH * AST];   // A^T [k][r]
    const int t = threadIdx.x;
    const int tx = t & 31;           // output cols 4*tx..4*tx+3
    const int ty = t >> 5;           // rows 8*ty..8*ty+7
    const int lane = t & 63, w = t >> 6;
    const int row0 = blockIdx.x * TR;

#pragma unroll
    for (int i = 0; i < 8; ++i) {
        int r = (i & 3) * 16 + (lane & 15);
        int k4 = ((i >> 2) * 4 + w) * 4 + (lane >> 4);
        float4 v = {0.f, 0.f, 0.f, 0.f};
        if (row0 + r < nrows)
            v = ((const float4*)(A + (size_t)(row0 + r) * HH))[k4];
        int k = k4 * 4;
        As[(k + 0) * AST + r] = v.x;
        As[(k + 1) * AST + r] = v.y;
        As[(k + 2) * AST + r] = v.z;
        As[(k + 3) * AST + r] = v.w;
    }
    __syncthreads();

    float acc[8][4];
#pragma unroll
    for (int ii = 0; ii < 8; ++ii)
#pragma unroll
        for (int j = 0; j < 4; ++j) acc[ii][j] = 0.f;

    const float4* W4 = (const float4*)Wp;   // row k -> W4[k*32 + tx]
    float4 wbuf[4];
#pragma unroll
    for (int kk = 0; kk < 4; ++kk) wbuf[kk] = W4[kk * 32 + tx];

    for (int k0 = 0; k0 < HH; k0 += 4) {
        float4 wn[4];
        const bool more = (k0 + 4 < HH);
#pragma unroll
        for (int kk = 0; kk < 4; ++kk) {
            if (more) wn[kk] = W4[(k0 + 4 + kk) * 32 + tx];  // prefetch next chunk
            int k = k0 + kk;
            const float* ap = &As[k * AST + ty * 8];
            float4 a0 = *(const float4*)ap;
            float4 a1 = *(const float4*)(ap + 4);
            float a[8] = {a0.x, a0.y, a0.z, a0.w, a1.x, a1.y, a1.z, a1.w};
#pragma unroll
            for (int ii = 0; ii < 8; ++ii) {
                acc[ii][0] += a[ii] * wbuf[kk].x;
                acc[ii][1] += a[ii] * wbuf[kk].y;
                acc[ii][2] += a[ii] * wbuf[kk].z;
                acc[ii][3] += a[ii] * wbuf[kk].w;
            }
        }
        if (more) {
#pragma unroll
            for (int kk = 0; kk < 4; ++kk) wbuf[kk] = wn[kk];
        }
    }

    float4 b4 = {0.f, 0.f, 0.f, 0.f};
    if (bias) b4 = ((const float4*)bias)[tx];
    float cs[4] = {0.f, 0.f, 0.f, 0.f}, cq[4] = {0.f, 0.f, 0.f, 0.f};
    const bool doStats = (statsp != nullptr);
#pragma unroll
    for (int ii = 0; ii < 8; ++ii) {
        int r = row0 + ty * 8 + ii;
        if (r < nrows) {
            float4 v = {acc[ii][0] + b4.x, acc[ii][1] + b4.y,
                        acc[ii][2] + b4.z, acc[ii][3] + b4.w};
            ((float4*)out)[(size_t)r * 32 + tx] = v;
            if (doStats) {
                cs[0] += v.x; cq[0] += v.x * v.x;
                cs[1] += v.y; cq[1] += v.y * v.y;
                cs[2] += v.z; cq[2] += v.z * v.z;
                cs[3] += v.w; cq[3] += v.w * v.w;
            }
        }
    }
    if (doStats) {
        __syncthreads();              // all waves done with As -> reuse as scratch
        float* red = As;              // [0..1023]=sum, [1024..2047]=sumsq
#pragma unroll
        for (int j = 0; j < 4; ++j) {
            red[ty * 128 + tx * 4 + j] = cs[j];
            red[1024 + ty * 128 + tx * 4 + j] = cq[j];
        }
        __syncthreads();
        if (t < 128) {
            float s = 0.f, q = 0.f;
#pragma unroll
            for (int g = 0; g < 8; ++g) {
                s += red[g * 128 + t];
                q += red[1024 + g * 128 + t];
            }
            atomicAdd(&statsp[t], s);
            atomicAdd(&statsp[128 + t], q);
        }
    }
}

// ---------------------------------------------------------------------------
// JumpingKnowledge GEMM: out = concat(z0..z3)[N,512] @ Wjk[512,128] + bjk
// Round-0 verbatim (verified 262us / VALUBusy 54% / no scratch).
// out may alias z0.
__global__ __launch_bounds__(256, 4) void gemm_jk(
    const float* __restrict__ z0, const float* __restrict__ z1,
    const float* __restrict__ z2, const float* __restrict__ z3,
    const float* __restrict__ Wjk, const float* __restrict__ bjk,
    float* __restrict__ out, int nrows)
{
    __shared__ float As[HH * AST];
    const int t = threadIdx.x;
    const int tx = t & 31;
    const int ty = t >> 5;
    const int lane = t & 63, w = t >> 6;
    const int row0 = blockIdx.x * TR;

    float acc[8][4];
#pragma unroll
    for (int ii = 0; ii < 8; ++ii)
#pragma unroll
        for (int j = 0; j < 4; ++j) acc[ii][j] = 0.f;

    const float* srcs[4] = {z0, z1, z2, z3};
    for (int j = 0; j < 4; ++j) {
        if (j) __syncthreads();
        const float* Z = srcs[j];
#pragma unroll
        for (int i = 0; i < 8; ++i) {
            int r = (i & 3) * 16 + (lane & 15);
            int k4 = ((i >> 2) * 4 + w) * 4 + (lane >> 4);
            float4 v = {0.f, 0.f, 0.f, 0.f};
            if (row0 + r < nrows)
                v = ((const float4*)(Z + (size_t)(row0 + r) * HH))[k4];
            int k = k4 * 4;
            As[(k + 0) * AST + r] = v.x;
            As[(k + 1) * AST + r] = v.y;
            As[(k + 2) * AST + r] = v.z;
            As[(k + 3) * AST + r] = v.w;
        }
        __syncthreads();

        const float4* W4 = (const float4*)(Wjk + (size_t)j * 128 * HH);
        float4 wbuf[4];
#pragma unroll
        for (int kk = 0; kk < 4; ++kk) wbuf[kk] = W4[kk * 32 + tx];

        for (int k0 = 0; k0 < HH; k0 += 4) {
            float4 wn[4];
            const bool more = (k0 + 4 < HH);
#pragma unroll
            for (int kk = 0; kk < 4; ++kk) {
                if (more) wn[kk] = W4[(k0 + 4 + kk) * 32 + tx];
                int k = k0 + kk;
                const float* ap = &As[k * AST + ty * 8];
                float4 a0 = *(const float4*)ap;
                float4 a1 = *(const float4*)(ap + 4);
                float a[8] = {a0.x, a0.y, a0.z, a0.w, a1.x, a1.y, a1.z, a1.w};
#pragma unroll
                for (int ii = 0; ii < 8; ++ii) {
                    acc[ii][0] += a[ii] * wbuf[kk].x;
                    acc[ii][1] += a[ii] * wbuf[kk].y;
                    acc[ii][2] += a[ii] * wbuf[kk].z;
                    acc[ii][3] += a[ii] * wbuf[kk].w;
                }
            }
            if (more) {
#pragma unroll
                for (int kk = 0; kk < 4; ++kk) wbuf[kk] = wn[kk];
            }
        }
    }

    float4 b4 = ((const float4*)bjk)[tx];
#pragma unroll
    for (int ii = 0; ii < 8; ++ii) {
        int r = row0 + ty * 8 + ii;
        if (r < nrows) {
            float4 v = {acc[ii][0] + b4.x, acc[ii][1] + b4.y,
                        acc[ii][2] + b4.z, acc[ii][3] + b4.w};
            ((float4*)out)[(size_t)r * 32 + tx] = v;
        }
    }
}

// ---------------------------------------------------------------------------
extern "C" void kernel_launch(void* const* d_in, const int* in_sizes, int n_in,
                              void* d_out, int out_size, void* d_ws, size_t ws_size,
                              hipStream_t stream)
{
    const float* x       = (const float*)d_in[0];
    const float* W_in    = (const float*)d_in[1];
    const float* b_in    = (const float*)d_in[2];
    const float* conv_W  = (const float*)d_in[3];
    const float* bn_g    = (const float*)d_in[4];
    const float* bn_b    = (const float*)d_in[5];
    const float* W_jk    = (const float*)d_in[6];
    const float* b_jk    = (const float*)d_in[7];
    const void*  srcp    = d_in[8];
    const void*  dstp    = d_in[9];

    // Workspace: 5*NH floats (244 MiB) + stats3 + CSR (~7.3 MB) + Wp (384 KB)
    float* ws     = (float*)d_ws;
    float* x0     = ws;                        // [N,H] z0, residual
    float* msg    = ws + (size_t)NH;           // [N,H] gather target (folded)
    float* zs0    = ws + 2 * (size_t)NH;       // z per layer; zs0 reused as JK out
    float* zs1    = ws + 3 * (size_t)NH;
    float* zs2    = ws + 4 * (size_t)NH;
    float* stats3 = ws + 5 * (size_t)NH;       // [3][256] sum/sumsq per BN layer
    int*   flag       = (int*)(stats3 + 768);
    int*   hist       = flag + 1;              // [NN]
    int*   incl       = hist + NN;             // [NN]
    int*   row_ptr    = incl + NN;             // [NN+1]
    int*   cursor     = row_ptr + NN + 1;      // [NN]
    int*   bsum       = cursor + NN;           // [NBLK]
    int*   sorted_src = bsum + NBLK + 1;       // [EE]
    float* Wp         = (float*)(sorted_src + EE);  // [6][128][128]

    const int GEMM_GRID = (NN + TR - 1) / TR;     // 1563
    const int EDGE_GRID = (EE + 255) / 256;       // 6250
    const int NODE_GRID = (NN + 3) / 4;           // 25000

    // ---- CSR build + weight prep + stats zero (once per launch) ----
    detect_idx64<<<1, 1, 0, stream>>>((const int*)srcp, flag);
    zero_int_k<<<(NN + 255) / 256, 256, 0, stream>>>(hist, NN);
    zero_f4_k<<<1, 192, 0, stream>>>((float4*)stats3, 192);
    hist_k<<<EDGE_GRID, 256, 0, stream>>>(dstp, flag, hist);
    scan1_k<<<NBLK, SCAN_B, 0, stream>>>(hist, incl, bsum);
    scan2_k<<<1, 512, 0, stream>>>(bsum);
    scan3_k<<<NBLK, SCAN_B, 0, stream>>>(hist, incl, bsum, row_ptr, cursor);
    fill_k<<<EDGE_GRID, 256, 0, stream>>>(srcp, dstp, flag, cursor, sorted_src);
    prep_w<<<dim3(64, 6), 256, 0, stream>>>(W_in, conv_W, Wp);

    // ---- x0 = x @ W_in + b_in ----
    gemm128<<<GEMM_GRID, 256, 0, stream>>>(x, Wp, b_in, x0, nullptr, NN);

    const float* act = x0;
    const float* stats_cur = nullptr;   // BN stats for act (null = no BN)
    const float* g_cur = nullptr;
    const float* b_cur = nullptr;

    for (int i = 0; i < 5; ++i) {
        // msg = (1-alpha)*segment_sum(act[src]) + alpha*x0   (BN fused on load)
        gather_k<<<NODE_GRID, 256, 0, stream>>>(act, row_ptr, sorted_src,
                                                stats_cur, g_cur, b_cur, x0, msg);

        float* zraw = (i >= 3) ? (float*)d_out : (zs0 + (size_t)i * NH);
        float* stats_next = (i < 3) ? (stats3 + (size_t)i * 256) : nullptr;
        gemm128<<<GEMM_GRID, 256, 0, stream>>>(msg, Wp + (size_t)(i + 1) * 16384,
                                               nullptr, zraw, stats_next, NN);
        if (i < 3) {
            act = zraw;                 // BN+ReLU fused into next gather
            stats_cur = stats_next;
            g_cur = bn_g + (size_t)i * HH;
            b_cur = bn_b + (size_t)i * HH;
        } else if (i == 3) {
            gemm_jk<<<GEMM_GRID, 256, 0, stream>>>(zs0, zs1, zs2,
                                                   (const float*)d_out, W_jk, b_jk,
                                                   zs0, NN);
            act = zs0;
            stats_cur = nullptr;
            g_cur = nullptr;
            b_cur = nullptr;
        }
    }
}